// Round 4
// baseline (82.803 us; speedup 1.0000x reference)
//
#include <hip/hip_runtime.h>

// 8-qubit statevector sim. R5 layout: 2 samples per wave64 -> 32 lanes/sample,
// 8 amps/lane. Amp index i (8 bits, qubit q <-> amp bit 7-q):
//   amp bits 7..3 -> lane bits 4..0 (qubits 0..4), amp bits 2..0 -> reg bits (qubits 5..7).
// CNOT chains deferred into gate conjugation masks (validated R1-R4):
//   layer-l gate on qubit q pairs i with i^m, m = sum_d (l&d)==d of bit(7-q-d)
//   row selector s = sum_d selon(l,d) of bit(7-(q-d))
// Fused U = RZ*RY*RX has u11=conj(u00), u10=-conj(u01) => row select = sign flips
// on Im(u00), Re(u01), folded into per-variant coefficient pairs.
//
// Ladder: R1 swizzle ~39us; R2 all-DPP 48 (VALU-saturated); R3/R4 packed VOP3P
// ~38 regardless of asm fusion -> NOT issue-bound (floor ~12us), stall-bound at
// 4 waves/SIMD (grid 4096 waves / 1024 SIMDs, occupancy 25%).
// R5: halve per-wave work, double waves: 8192 waves = 8 blocks/CU = 32 waves/CU
// (100% occupancy) via __launch_bounds__(256,8). Total VALU work conserved;
// 2x TLP to cover exchange latency + FMA-chain latency.
// Measurement masks (deferred-CNOT observable rows, amp-bit sets):
//   q0..q3: {7},{6},{5},{4}; q4: {7,3}; q5: {6,2}; q6: {5,1}; q7: {4,0}.
//   q0..q4 fully lane-side -> 5-stage WHT, read at il=16,8,4,2,17.
//   q5..q7: reg-signed sums Ab2/Ab1/Ab0 with lane signs bit3/bit2/bit1, full sum.

#define NGATES 32

typedef float v2f __attribute__((ext_vector_type(2)));

__device__ __forceinline__ v2f mk2(float a, float b) { v2f t; t.x = a; t.y = b; return t; }

constexpr bool selon(int l, int d) {
    return (l == 0) ? (d == 0) : (((d + l - 1) & (l - 1)) == (l - 1));
}
// full 8-bit pair mask over amp bits
constexpr int fpm(int l, int q) {
    int m = 0;
    for (int d = 0; q + d <= 7; ++d)
        if ((l & d) == d) m |= 1 << (7 - (q + d));
    return m;
}
// full 8-bit selector mask over amp bits
constexpr int fsm(int l, int q) {
    int m = 0;
    for (int d = 0; d <= q; ++d)
        if (selon(l, d)) m |= 1 << (7 - (q - d));
    return m;
}
// lane part = amp bits 7..3 -> lane bits 4..0 ; reg part = amp bits 2..0
constexpr int lm_of (int l, int q) { return fpm(l, q) >> 3; }
constexpr int rm_of (int l, int q) { return fpm(l, q) & 7;  }
constexpr int slm_of(int l, int q) { return fsm(l, q) >> 3; }
constexpr int srm_of(int l, int q) { return fsm(l, q) & 7;  }

__device__ __forceinline__ float xsgn(float f, unsigned m) {
    return __int_as_float(__float_as_int(f) ^ (int)m);
}

// ---- cross-lane xor exchange ----
// DPP for masks 1..15 (within 16-lane rows; our 32-lane sample = 2 rows, xor<16
// stays in-row). Single-mov set {1,2,3,7,8,15}; composites = 2 chained movs.
// Masks >=16 -> ds_swizzle (BitMode xor, and_mask 0x1F = native 32-lane groups).
template<int C>
__device__ __forceinline__ int dppmov(int x) {
    return __builtin_amdgcn_update_dpp(x, x, C, 0xF, 0xF, false);
}
template<int M>
__device__ __forceinline__ float shx_dpp(float v) {
    int x = __float_as_int(v);
    if constexpr (M == 1)       { x = dppmov<0xB1>(x); }
    else if constexpr (M == 2)  { x = dppmov<0x4E>(x); }
    else if constexpr (M == 3)  { x = dppmov<0x1B>(x); }
    else if constexpr (M == 4)  { x = dppmov<0x1B>(x);  x = dppmov<0x141>(x); } // 3^7
    else if constexpr (M == 5)  { x = dppmov<0x4E>(x);  x = dppmov<0x141>(x); } // 2^7
    else if constexpr (M == 6)  { x = dppmov<0xB1>(x);  x = dppmov<0x141>(x); } // 1^7
    else if constexpr (M == 7)  { x = dppmov<0x141>(x); }
    else if constexpr (M == 8)  { x = dppmov<0x128>(x); }
    else if constexpr (M == 9)  { x = dppmov<0xB1>(x);  x = dppmov<0x128>(x); } // 1^8
    else if constexpr (M == 10) { x = dppmov<0x4E>(x);  x = dppmov<0x128>(x); } // 2^8
    else if constexpr (M == 11) { x = dppmov<0x1B>(x);  x = dppmov<0x128>(x); } // 3^8
    else if constexpr (M == 12) { x = dppmov<0x140>(x); x = dppmov<0x1B>(x);  } // 15^3
    else if constexpr (M == 13) { x = dppmov<0x140>(x); x = dppmov<0x4E>(x);  } // 15^2
    else if constexpr (M == 14) { x = dppmov<0x140>(x); x = dppmov<0xB1>(x);  } // 15^1
    else                        { x = dppmov<0x140>(x); }                        // 15
    return __int_as_float(x);
}
template<int M>
__device__ __forceinline__ float shx_ds(float v) {
    return __int_as_float(__builtin_amdgcn_ds_swizzle(__float_as_int(v), (M << 10) | 0x1F));
}
template<int M>
__device__ __forceinline__ float shxm(float v) {
    if constexpr (M < 16) return shx_dpp<M>(v);
    else                  return shx_ds<M>(v);
}

// ---- packed complex gate update (4 VOP3P ops, validated R3/R4) ----
// lo: c0r*ar - c0i*ai + c1r*br - c1i*bi ; hi: c0r*ai + c0i*ar + c1r*bi + c1i*br
__device__ __forceinline__ v2f cplx4(v2f K0, v2f K1, v2f A, v2f B) {
    v2f n;
    asm("v_pk_mul_f32 %0, %1, %2 op_sel:[0,0] op_sel_hi:[0,1]"
        : "=v"(n) : "v"(K0), "v"(A));
    asm("v_pk_fma_f32 %0, %1, %2, %0 op_sel:[1,1,0] op_sel_hi:[1,0,1] neg_lo:[1,0,0]"
        : "+v"(n) : "v"(K0), "v"(A));
    asm("v_pk_fma_f32 %0, %1, %2, %0 op_sel:[0,0,0] op_sel_hi:[0,1,1]"
        : "+v"(n) : "v"(K1), "v"(B));
    asm("v_pk_fma_f32 %0, %1, %2, %0 op_sel:[1,1,0] op_sel_hi:[1,0,1] neg_lo:[1,0,0]"
        : "+v"(n) : "v"(K1), "v"(B));
    return n;
}

template<int LM, int RM, int SLM, int SRM>
__device__ __forceinline__ void apply_gate(v2f A[8], int lane, const float4 g)
{
    unsigned sm = 0;
    if constexpr (SLM != 0)
        sm = (unsigned)((__builtin_popcount(lane & SLM) & 1) << 31);
    // coefficient pairs, row-variant v in {0,1}: K0[v]=(c0r, c0i_v), K1[v]=(c1r_v, c1i)
    v2f K0[2], K1[2];
    K0[0] = mk2(g.x, xsgn(g.y, sm));
    K0[1] = mk2(g.x, xsgn(g.y, sm ^ 0x80000000u));
    K1[0] = mk2(xsgn(g.z, sm), g.w);
    K1[1] = mk2(xsgn(g.z, sm ^ 0x80000000u), g.w);

    if constexpr (RM == 0) {
        // pure cross-lane: each r independent, partner = permuted self-register
        #pragma unroll
        for (int r = 0; r < 8; ++r) {
            const int v = __builtin_popcount(r & SRM) & 1;   // compile-time per r
            v2f B = mk2(shxm<LM>(A[r].x), shxm<LM>(A[r].y));
            A[r] = cplx4(K0[v], K1[v], A[r], B);
        }
    } else {
        // register pairs {r, r^RM}; fetch olds (permuted if LM!=0), update both
        #pragma unroll
        for (int r = 0; r < 8; ++r) {
            const int p = r ^ RM;
            if (p < r) continue;
            v2f Br, Bp;
            if constexpr (LM != 0) {
                Br = mk2(shxm<LM>(A[p].x), shxm<LM>(A[p].y));
                Bp = mk2(shxm<LM>(A[r].x), shxm<LM>(A[r].y));
            } else {
                Br = A[p];
                Bp = A[r];
            }
            const int vr = __builtin_popcount(r & SRM) & 1;
            const int vp = __builtin_popcount(p & SRM) & 1;
            v2f nr = cplx4(K0[vr], K1[vr], A[r], Br);
            v2f np = cplx4(K0[vp], K1[vp], A[p], Bp);
            A[r] = nr; A[p] = np;
        }
    }
}

#define GATE(L, Q) apply_gate<lm_of(L,Q), rm_of(L,Q), slm_of(L,Q), srm_of(L,Q)>( \
                       A, lane, gsh4[(L)*8+(Q)])
#define LAYER(L) GATE(L,0); GATE(L,1); GATE(L,2); GATE(L,3); \
                 GATE(L,4); GATE(L,5); GATE(L,6); GATE(L,7);

__global__ __launch_bounds__(256, 8) void qsim(const float* __restrict__ x,
                                               const float* __restrict__ w,
                                               float* __restrict__ out, int B)
{
    __shared__ float4 gsh4[NGATES];  // u00r,u00i,u01r,u01i (row1 = conj structure)

    const int tid = threadIdx.x;
    if (tid < NGATES) {
        float hx = 0.5f * w[tid*3+0];
        float hy = 0.5f * w[tid*3+1];
        float hz = 0.5f * w[tid*3+2];
        float cx = cosf(hx), sx = sinf(hx);
        float cy = cosf(hy), sy = sinf(hy);
        float cz = cosf(hz), sz = sinf(hz);
        // M = RY*RX ; U = RZ*M (row0 only; u11=conj(u00), u10=-conj(u01))
        float m00r = cy*cx,  m00i =  sy*sx;
        float m01r = -sy*cx, m01i = -cy*sx;
        gsh4[tid] = make_float4(cz*m00r + sz*m00i,
                                cz*m00i - sz*m00r,
                                cz*m01r + sz*m01i,
                                cz*m01i - sz*m01r);
    }
    __syncthreads();

    const int lane = tid & 63;
    const int il   = lane & 31;                 // in-sample lane index (amp bits 7:3)
    const int sample = blockIdx.x * 8 + (tid >> 5);
    if (sample >= B) return;

    // ---- encoding: product state ----
    const float4* xp = (const float4*)(x + sample * 8);
    float4 xa = xp[0], xb = xp[1];
    float xs[8] = {xa.x, xa.y, xa.z, xa.w, xb.x, xb.y, xb.z, xb.w};
    float cq[8], sq[8];
    #pragma unroll
    for (int q = 0; q < 8; ++q) {
        float h = 0.5f * xs[q];
        __sincosf(h, &sq[q], &cq[q]);
    }
    // lane product, qubits 0..4 (qubit q -> lane bit 4-q)
    float lp = ((il & 16) ? sq[0] : cq[0]);
    lp      *= ((il &  8) ? sq[1] : cq[1]);
    lp      *= ((il &  4) ? sq[2] : cq[2]);
    lp      *= ((il &  2) ? sq[3] : cq[3]);
    lp      *= ((il &  1) ? sq[4] : cq[4]);
    // register tree, qubits 5..7 (reg bit2=q5, b1=q6, b0=q7)
    float t67[4] = {cq[6]*cq[7], cq[6]*sq[7], sq[6]*cq[7], sq[6]*sq[7]};
    float a5[2]  = {cq[5]*lp, sq[5]*lp};
    v2f A[8];
    #pragma unroll
    for (int r = 0; r < 8; ++r)
        A[r] = mk2(a5[(r >> 2) & 1] * t67[r & 3], 0.f);

    // ---- 4 layers of fused gates (CNOTs deferred) ----
    LAYER(0)
    LAYER(1)
    LAYER(2)
    LAYER(3)

    // ---- measurement ----
    float p[8];
    #pragma unroll
    for (int r = 0; r < 8; ++r) p[r] = A[r].x*A[r].x + A[r].y*A[r].y;

    // register-level signed sums over reg bits (amp bits 2..0)
    float s0[4], d0[4];
    #pragma unroll
    for (int k = 0; k < 4; ++k) { s0[k] = p[2*k] + p[2*k+1]; d0[k] = p[2*k] - p[2*k+1]; }
    float Ab0 = (d0[0]+d0[1]) + (d0[2]+d0[3]);   // sign on amp bit0
    float s1a = s0[0] + s0[1], s1b = s0[2] + s0[3];
    float Ab1 = (s0[0]-s0[1]) + (s0[2]-s0[3]);   // sign on amp bit1
    float Ab2 = s1a - s1b;                       // sign on amp bit2
    float P   = s1a + s1b;

    // per-lane sign bitmasks for lane bits (lane bit k = amp bit k+3)
    const unsigned sg1  = (unsigned)(il & 1)  << 31;
    const unsigned sg2  = (unsigned)(il & 2)  << 30;
    const unsigned sg4  = (unsigned)(il & 4)  << 29;
    const unsigned sg8  = (unsigned)(il & 8)  << 28;
    const unsigned sg16 = (unsigned)(il & 16) << 27;

    // 5-stage WHT of P over the 32-lane group: lane j holds sum_i (-1)^{i.j} P_i
    float wP = P;
    { float t = shxm<1>(wP);  wP = t + xsgn(wP, sg1);  }
    { float t = shxm<2>(wP);  wP = t + xsgn(wP, sg2);  }
    { float t = shxm<4>(wP);  wP = t + xsgn(wP, sg4);  }
    { float t = shxm<8>(wP);  wP = t + xsgn(wP, sg8);  }
    { float t = shxm<16>(wP); wP = t + xsgn(wP, sg16); }
    // q0@il=16 {amp7}, q1@8 {amp6}, q2@4 {amp5}, q3@2 {amp4}, q4@17 {amp7,amp3}

    // q5..q7: lane-signed full sums (observable rows {6,2},{5,1},{4,0})
    float a5v = xsgn(Ab2, sg8);   // amp bit6 = lane bit3
    a5v += shxm<1>(a5v); a5v += shxm<2>(a5v); a5v += shxm<4>(a5v);
    a5v += shxm<8>(a5v); a5v += shxm<16>(a5v);
    float a6v = xsgn(Ab1, sg4);   // amp bit5 = lane bit2
    a6v += shxm<1>(a6v); a6v += shxm<2>(a6v); a6v += shxm<4>(a6v);
    a6v += shxm<8>(a6v); a6v += shxm<16>(a6v);
    float a7v = xsgn(Ab0, sg2);   // amp bit4 = lane bit1
    a7v += shxm<1>(a7v); a7v += shxm<2>(a7v); a7v += shxm<4>(a7v);
    a7v += shxm<8>(a7v); a7v += shxm<16>(a7v);

    float* op = out + sample * 8;
    if (il == 16)      { op[0] = wP; op[5] = a5v; }
    else if (il == 8)  { op[1] = wP; op[6] = a6v; }
    else if (il == 4)  { op[2] = wP; op[7] = a7v; }
    else if (il == 2)  { op[3] = wP; }
    else if (il == 17) { op[4] = wP; }
}

extern "C" void kernel_launch(void* const* d_in, const int* in_sizes, int n_in,
                              void* d_out, int out_size, void* d_ws, size_t ws_size,
                              hipStream_t stream) {
    const float* x = (const float*)d_in[0];
    const float* w = (const float*)d_in[1];
    float* out = (float*)d_out;
    const int B = in_sizes[0] / 8;           // 16384 samples
    const int blocks = (B + 7) / 8;          // 8 samples per 256-thread block
    qsim<<<blocks, 256, 0, stream>>>(x, w, out, B);
}

// Round 5
// 81.689 us; speedup vs baseline: 1.0136x; 1.0136x over previous
//
#include <hip/hip_runtime.h>

// 8-qubit statevector sim. 4 samples per wave64: 16 lanes/sample, 16 amps/lane.
// Amp index i (8 bits): qubit q<=3 -> lane bit (3-q); qubit q>=4 -> reg bit (7-q).
// CNOT chains deferred into gate conjugation masks (validated R0-R4):
//   layer-l gate on qubit q pairs i with i^m; row selector = parity(i & sel mask).
// Fused U = RZ*RY*RX has u11=conj(u00), u10=-conj(u01) => row select = sign flips
// on Im(u00), Re(u01).
//
// Ladder: R0 scalar+swizzle ~38us; R1 scalar+DPP 48 (VALU-saturated); R2/R3
// packed VOP3P ~38 (HALF the instructions, same time => v_pk_fma_f32 is not
// full-rate; packed fp32 is packaging, not throughput); R5 2x occupancy ~42
// (TLP not the limiter). Conclusion: reduce REAL work.
// R6: (a) fold layer 0 into encoding: layer-0 gates are plain per-qubit 2x2
//     (identity conjugation), so state = prod_q (alpha_q, beta_q) with
//     (alpha,beta) = U0q * (cos,sin)^T -- complex product tree replaces 8 of
//     32 gates (-25% gate work for ~33 extra cmuls);
// (b) scalar fp32 math (best measured) + hybrid exchange: single-DPP masks
//     {1,2,3,7,8,15} on VALU pipe, composite masks {4,5,6,10,12} on DS pipe.

#define NGATES 32

constexpr bool selon(int l, int d) {
    return (l == 0) ? (d == 0) : (((d + l - 1) & (l - 1)) == (l - 1));
}
// pair mask, lane part (qubits 0..3 -> lane bit 3-q)
constexpr int lm_of(int l, int q) {
    int m = 0;
    for (int d = 0; q + d <= 7; ++d)
        if ((l & d) == d) { int qq = q + d; if (qq <= 3) m |= 1 << (3 - qq); }
    return m;
}
// pair mask, register part (qubits 4..7 -> reg bit 7-q)
constexpr int rm_of(int l, int q) {
    int m = 0;
    for (int d = 0; q + d <= 7; ++d)
        if ((l & d) == d) { int qq = q + d; if (qq >= 4) m |= 1 << (7 - qq); }
    return m;
}
// selector mask, lane part
constexpr int slm_of(int l, int q) {
    int m = 0;
    for (int d = 0; d <= q; ++d)
        if (selon(l, d)) { int k = q - d; if (k <= 3) m |= 1 << (3 - k); }
    return m;
}
// selector mask, register part
constexpr int srm_of(int l, int q) {
    int m = 0;
    for (int d = 0; d <= q; ++d)
        if (selon(l, d)) { int k = q - d; if (k >= 4) m |= 1 << (7 - k); }
    return m;
}

__device__ __forceinline__ float xsgn(float f, unsigned m) {
    return __int_as_float(__float_as_int(f) ^ (int)m);
}

// ---- cross-lane xor exchange: hybrid DPP / ds_swizzle ----
template<int C>
__device__ __forceinline__ int dppmov(int x) {
    return __builtin_amdgcn_update_dpp(x, x, C, 0xF, 0xF, false);
}
template<int M>
__device__ __forceinline__ float shx_dpp(float v) {
    int x = __float_as_int(v);
    if constexpr (M == 1)       { x = dppmov<0xB1>(x); }
    else if constexpr (M == 2)  { x = dppmov<0x4E>(x); }
    else if constexpr (M == 3)  { x = dppmov<0x1B>(x); }
    else if constexpr (M == 7)  { x = dppmov<0x141>(x); }
    else if constexpr (M == 8)  { x = dppmov<0x128>(x); }
    else                        { x = dppmov<0x140>(x); }  // 15
    return __int_as_float(x);
}
template<int M>
__device__ __forceinline__ float shx_ds(float v) {
    return __int_as_float(__builtin_amdgcn_ds_swizzle(__float_as_int(v), (M << 10) | 0x1F));
}
constexpr bool sgl(int M) {
    return M == 1 || M == 2 || M == 3 || M == 7 || M == 8 || M == 15;
}
template<int M>
__device__ __forceinline__ float shxm(float v) {
    if constexpr (sgl(M)) return shx_dpp<M>(v);
    else                  return shx_ds<M>(v);
}

template<int LM, int RM, int SLM, int SRM>
__device__ __forceinline__ void apply_gate(float ar[16], float ai[16], int lane,
                                           const float4 g)  // u00r,u00i,u01r,u01i
{
    unsigned sm = 0;
    if constexpr (SLM != 0)
        sm = (unsigned)((__builtin_popcount(lane & SLM) & 1) << 31);
    const float c0r = g.x, c1i = g.w;
    const float c0i0 = xsgn(g.y, sm);
    const float c1r0 = xsgn(g.z, sm);
    const float c0i1 = xsgn(g.y, sm ^ 0x80000000u);
    const float c1r1 = xsgn(g.z, sm ^ 0x80000000u);

    if constexpr (RM == 0) {
        // pure cross-lane: each r independent, partner = permuted self-register
        #pragma unroll
        for (int r = 0; r < 16; ++r) {
            const bool c1 = (__builtin_popcount(r & SRM) & 1) != 0;  // compile-time
            const float c0i = c1 ? c0i1 : c0i0;
            const float c1r = c1 ? c1r1 : c1r0;
            const float br = shxm<LM>(ar[r]);
            const float bi = shxm<LM>(ai[r]);
            const float nr = c0r*ar[r] - c0i*ai[r] + c1r*br - c1i*bi;
            const float ni = c0r*ai[r] + c0i*ar[r] + c1r*bi + c1i*br;
            ar[r] = nr; ai[r] = ni;
        }
    } else {
        // register pairs {r, r^RM}; fetch olds (permuted if LM!=0), update both
        #pragma unroll
        for (int r = 0; r < 16; ++r) {
            const int p = r ^ RM;
            if (p < r) continue;
            float br_r, bi_r, br_p, bi_p;
            if constexpr (LM != 0) {
                br_r = shxm<LM>(ar[p]); bi_r = shxm<LM>(ai[p]);
                br_p = shxm<LM>(ar[r]); bi_p = shxm<LM>(ai[r]);
            } else {
                br_r = ar[p]; bi_r = ai[p];
                br_p = ar[r]; bi_p = ai[r];
            }
            const bool cr = (__builtin_popcount(r & SRM) & 1) != 0;
            const bool cp = (__builtin_popcount(p & SRM) & 1) != 0;
            const float c0i_r = cr ? c0i1 : c0i0, c1r_r = cr ? c1r1 : c1r0;
            const float c0i_p = cp ? c0i1 : c0i0, c1r_p = cp ? c1r1 : c1r0;
            const float nr_r = c0r*ar[r] - c0i_r*ai[r] + c1r_r*br_r - c1i*bi_r;
            const float ni_r = c0r*ai[r] + c0i_r*ar[r] + c1r_r*bi_r + c1i*br_r;
            const float nr_p = c0r*ar[p] - c0i_p*ai[p] + c1r_p*br_p - c1i*bi_p;
            const float ni_p = c0r*ai[p] + c0i_p*ar[p] + c1r_p*bi_p + c1i*br_p;
            ar[r] = nr_r; ai[r] = ni_r;
            ar[p] = nr_p; ai[p] = ni_p;
        }
    }
}

#define GATE(L, Q) apply_gate<lm_of(L,Q), rm_of(L,Q), slm_of(L,Q), srm_of(L,Q)>( \
                       ar, ai, lane, gsh4[(L)*8+(Q)])
#define LAYER(L) GATE(L,0); GATE(L,1); GATE(L,2); GATE(L,3); \
                 GATE(L,4); GATE(L,5); GATE(L,6); GATE(L,7);

__global__ __launch_bounds__(256, 4) void qsim(const float* __restrict__ x,
                                               const float* __restrict__ w,
                                               float* __restrict__ out, int B)
{
    __shared__ float4 gsh4[NGATES];  // u00r,u00i,u01r,u01i (row1 = conj structure)

    const int tid = threadIdx.x;
    if (tid < NGATES) {
        float hx = 0.5f * w[tid*3+0];
        float hy = 0.5f * w[tid*3+1];
        float hz = 0.5f * w[tid*3+2];
        float cx = cosf(hx), sx = sinf(hx);
        float cy = cosf(hy), sy = sinf(hy);
        float cz = cosf(hz), sz = sinf(hz);
        // M = RY*RX ; U = RZ*M (row0 only; u11=conj(u00), u10=-conj(u01))
        float m00r = cy*cx,  m00i =  sy*sx;
        float m01r = -sy*cx, m01i = -cy*sx;
        gsh4[tid] = make_float4(cz*m00r + sz*m00i,
                                cz*m00i - sz*m00r,
                                cz*m01r + sz*m01i,
                                cz*m01i - sz*m01r);
    }
    __syncthreads();

    const int lane = tid & 63;
    const int il   = lane & 15;                 // in-sample lane index (amp bits 7:4)
    const int sample = blockIdx.x * 16 + (tid >> 4);
    if (sample >= B) return;

    // ---- encoding + layer 0 folded: complex product state ----
    // Per qubit q: (alpha,beta) = U0q * (cos(x/2), sin(x/2))^T with
    // u10=-conj(u01), u11=conj(u00):
    //   alpha = (gx*c + gz*s,  gy*c + gw*s)
    //   beta  = (gx*s - gz*c,  gw*c - gy*s)
    const float4* xp = (const float4*)(x + sample * 8);
    float4 xa = xp[0], xb = xp[1];
    float xs[8] = {xa.x, xa.y, xa.z, xa.w, xb.x, xb.y, xb.z, xb.w};
    float arf[8], aif[8], brf[8], bif[8];
    #pragma unroll
    for (int q = 0; q < 8; ++q) {
        float c, s;
        __sincosf(0.5f * xs[q], &s, &c);
        const float4 g = gsh4[q];
        arf[q] = g.x*c + g.z*s;
        aif[q] = g.y*c + g.w*s;
        brf[q] = g.x*s - g.z*c;
        bif[q] = g.w*c - g.y*s;
    }
    // lane factor F = prod_{q=0..3} (lane bit 3-q ? beta : alpha), complex
    float Fr = (il & 8) ? brf[0] : arf[0];
    float Fi = (il & 8) ? bif[0] : aif[0];
    #pragma unroll
    for (int q = 1; q < 4; ++q) {
        const int bit = il & (8 >> q);
        const float gr = bit ? brf[q] : arf[q];
        const float gi = bit ? bif[q] : aif[q];
        const float nr = Fr*gr - Fi*gi;
        const float ni = Fr*gi + Fi*gr;
        Fr = nr; Fi = ni;
    }
    // register tree (complex): reg bit3=q4, b2=q5, b1=q6, b0=q7
    float t67r[4], t67i[4];
    #pragma unroll
    for (int b6 = 0; b6 < 2; ++b6)
        #pragma unroll
        for (int b7 = 0; b7 < 2; ++b7) {
            const float x6r = b6 ? brf[6] : arf[6], x6i = b6 ? bif[6] : aif[6];
            const float x7r = b7 ? brf[7] : arf[7], x7i = b7 ? bif[7] : aif[7];
            t67r[b6*2+b7] = x6r*x7r - x6i*x7i;
            t67i[b6*2+b7] = x6r*x7i + x6i*x7r;
        }
    float v57r[8], v57i[8];
    #pragma unroll
    for (int b5 = 0; b5 < 2; ++b5) {
        const float x5r = b5 ? brf[5] : arf[5], x5i = b5 ? bif[5] : aif[5];
        #pragma unroll
        for (int k = 0; k < 4; ++k) {
            v57r[b5*4+k] = x5r*t67r[k] - x5i*t67i[k];
            v57i[b5*4+k] = x5r*t67i[k] + x5i*t67r[k];
        }
    }
    float b4r[2], b4i[2];
    #pragma unroll
    for (int b4 = 0; b4 < 2; ++b4) {
        const float x4r = b4 ? brf[4] : arf[4], x4i = b4 ? bif[4] : aif[4];
        b4r[b4] = x4r*Fr - x4i*Fi;
        b4i[b4] = x4r*Fi + x4i*Fr;
    }
    float ar[16], ai[16];
    #pragma unroll
    for (int r = 0; r < 16; ++r) {
        const int hi = (r >> 3) & 1, lo = r & 7;
        ar[r] = b4r[hi]*v57r[lo] - b4i[hi]*v57i[lo];
        ai[r] = b4r[hi]*v57i[lo] + b4i[hi]*v57r[lo];
    }

    // ---- layers 1..3 of fused gates (CNOTs deferred; layer 0 folded above) ----
    LAYER(1)
    LAYER(2)
    LAYER(3)

    // ---- measurement ----
    float p[16];
    #pragma unroll
    for (int r = 0; r < 16; ++r) p[r] = ar[r]*ar[r] + ai[r]*ai[r];

    // register-level signed sums: A_k = sum_r (-1)^{bit k of r} p[r]
    float s0[8], d0[8];
    #pragma unroll
    for (int k = 0; k < 8; ++k) { s0[k] = p[2*k] + p[2*k+1]; d0[k] = p[2*k] - p[2*k+1]; }
    float A0 = ((d0[0]+d0[1]) + (d0[2]+d0[3])) + ((d0[4]+d0[5]) + (d0[6]+d0[7]));
    float s1[4], d1[4];
    #pragma unroll
    for (int k = 0; k < 4; ++k) { s1[k] = s0[2*k] + s0[2*k+1]; d1[k] = s0[2*k] - s0[2*k+1]; }
    float A1 = (d1[0]+d1[1]) + (d1[2]+d1[3]);
    float s2[2], d2[2];
    #pragma unroll
    for (int k = 0; k < 2; ++k) { s2[k] = s1[2*k] + s1[2*k+1]; d2[k] = s1[2*k] - s1[2*k+1]; }
    float A2 = d2[0] + d2[1];
    float A3 = s2[0] - s2[1];
    float P  = s2[0] + s2[1];

    // per-lane sign bitmasks for lane bits
    const unsigned sg1 = (unsigned)(il & 1) << 31;
    const unsigned sg2 = (unsigned)(il & 2) << 30;
    const unsigned sg4 = (unsigned)(il & 4) << 29;
    const unsigned sg8 = (unsigned)(il & 8) << 28;

    // 4-stage WHT of P over the 16-lane group: lane j holds sum_i (-1)^{i.j} P_i
    float wP = P;
    { float t = shxm<1>(wP); wP = t + xsgn(wP, sg1); }
    { float t = shxm<2>(wP); wP = t + xsgn(wP, sg2); }
    { float t = shxm<4>(wP); wP = t + xsgn(wP, sg4); }
    { float t = shxm<8>(wP); wP = t + xsgn(wP, sg8); }
    // v0 at il=8, v1 at il=4, v2 at il=2, v3 at il=1

    // signed lane sums for v4..v7 (sign = one lane bit), result in all lanes
    float a3 = xsgn(A3, sg8);
    a3 += shxm<1>(a3); a3 += shxm<2>(a3); a3 += shxm<4>(a3); a3 += shxm<8>(a3);
    float a2 = xsgn(A2, sg4);
    a2 += shxm<1>(a2); a2 += shxm<2>(a2); a2 += shxm<4>(a2); a2 += shxm<8>(a2);
    float a1 = xsgn(A1, sg2);
    a1 += shxm<1>(a1); a1 += shxm<2>(a1); a1 += shxm<4>(a1); a1 += shxm<8>(a1);
    float a0 = xsgn(A0, sg1);
    a0 += shxm<1>(a0); a0 += shxm<2>(a0); a0 += shxm<4>(a0); a0 += shxm<8>(a0);

    float* op = out + sample * 8;
    if (il == 8)      { op[0] = wP; op[4] = a3; }
    else if (il == 4) { op[1] = wP; op[5] = a2; }
    else if (il == 2) { op[2] = wP; op[6] = a1; }
    else if (il == 1) { op[3] = wP; op[7] = a0; }
}

extern "C" void kernel_launch(void* const* d_in, const int* in_sizes, int n_in,
                              void* d_out, int out_size, void* d_ws, size_t ws_size,
                              hipStream_t stream) {
    const float* x = (const float*)d_in[0];
    const float* w = (const float*)d_in[1];
    float* out = (float*)d_out;
    const int B = in_sizes[0] / 8;           // 16384 samples
    const int blocks = (B + 15) / 16;        // 16 samples per 256-thread block
    qsim<<<blocks, 256, 0, stream>>>(x, w, out, B);
}

// Round 7
// 80.351 us; speedup vs baseline: 1.0305x; 1.0167x over previous
//
#include <hip/hip_runtime.h>

// 8-qubit statevector sim. 4 samples per wave64: 16 lanes/sample, 16 amps/lane.
// Amp index i (8 bits): qubit q<=3 -> lane bit (3-q); qubit q>=4 -> reg bit (7-q).
// CNOT chains deferred into gate conjugation masks (validated R0-R6):
//   layer-l gate on qubit q pairs i with i^m; row selector = parity(i & sel mask).
// Fused U = RZ*RY*RX has u11=conj(u00), u10=-conj(u01) => row select = sign flips
// on Im(u00), Re(u01). Layer 0 folded into encoding (R6, validated): per qubit
// (alpha,beta) = U0q*(cos,sin)^T, state = complex product tree; 24 gates remain.
//
// Ladder: R0 scalar+swizzle 38.3; R1 all-DPP 48 (VALU-saturated); R2/R3 packed
// VOP3P 38.3 (half the insts, same time); R5 2x occupancy 42; R6 fold+hybrid
// 41.5 but VALU busy 35->25us. Conclusion: stall-bound. VGPR_Count=36 with 32
// live amps => compiler serializes each gate's exchange->FMA chain (no regs to
// interleave 16 amps) + VALU->DPP read hazard s_nops.
// R7: gather-then-math split in apply_gate: phase 1 gathers ALL partner values
// into br[16]/bi[16] (batched exchanges, +32 live regs, budget is 128), phase 2
// does 16 independent 2x2 updates (16-way ILP; DPP sources >=16 insts old).
// (R7 submission hit an infra failure -- container died before running;
//  this is an identical resubmit.)

#define NGATES 32

constexpr bool selon(int l, int d) {
    return (l == 0) ? (d == 0) : (((d + l - 1) & (l - 1)) == (l - 1));
}
// pair mask, lane part (qubits 0..3 -> lane bit 3-q)
constexpr int lm_of(int l, int q) {
    int m = 0;
    for (int d = 0; q + d <= 7; ++d)
        if ((l & d) == d) { int qq = q + d; if (qq <= 3) m |= 1 << (3 - qq); }
    return m;
}
// pair mask, register part (qubits 4..7 -> reg bit 7-q)
constexpr int rm_of(int l, int q) {
    int m = 0;
    for (int d = 0; q + d <= 7; ++d)
        if ((l & d) == d) { int qq = q + d; if (qq >= 4) m |= 1 << (7 - qq); }
    return m;
}
// selector mask, lane part
constexpr int slm_of(int l, int q) {
    int m = 0;
    for (int d = 0; d <= q; ++d)
        if (selon(l, d)) { int k = q - d; if (k <= 3) m |= 1 << (3 - k); }
    return m;
}
// selector mask, register part
constexpr int srm_of(int l, int q) {
    int m = 0;
    for (int d = 0; d <= q; ++d)
        if (selon(l, d)) { int k = q - d; if (k >= 4) m |= 1 << (7 - k); }
    return m;
}

__device__ __forceinline__ float xsgn(float f, unsigned m) {
    return __int_as_float(__float_as_int(f) ^ (int)m);
}

// ---- cross-lane xor exchange: hybrid DPP / ds_swizzle ----
template<int C>
__device__ __forceinline__ int dppmov(int x) {
    return __builtin_amdgcn_update_dpp(x, x, C, 0xF, 0xF, false);
}
template<int M>
__device__ __forceinline__ float shx_dpp(float v) {
    int x = __float_as_int(v);
    if constexpr (M == 1)       { x = dppmov<0xB1>(x); }
    else if constexpr (M == 2)  { x = dppmov<0x4E>(x); }
    else if constexpr (M == 3)  { x = dppmov<0x1B>(x); }
    else if constexpr (M == 7)  { x = dppmov<0x141>(x); }
    else if constexpr (M == 8)  { x = dppmov<0x128>(x); }
    else                        { x = dppmov<0x140>(x); }  // 15
    return __int_as_float(x);
}
template<int M>
__device__ __forceinline__ float shx_ds(float v) {
    return __int_as_float(__builtin_amdgcn_ds_swizzle(__float_as_int(v), (M << 10) | 0x1F));
}
constexpr bool sgl(int M) {
    return M == 1 || M == 2 || M == 3 || M == 7 || M == 8 || M == 15;
}
template<int M>
__device__ __forceinline__ float shxm(float v) {
    if constexpr (sgl(M)) return shx_dpp<M>(v);
    else                  return shx_ds<M>(v);
}

template<int LM, int RM, int SLM, int SRM>
__device__ __forceinline__ void apply_gate(float ar[16], float ai[16], int lane,
                                           const float4 g)  // u00r,u00i,u01r,u01i
{
    unsigned sm = 0;
    if constexpr (SLM != 0)
        sm = (unsigned)((__builtin_popcount(lane & SLM) & 1) << 31);
    const float c0r = g.x, c1i = g.w;
    const float c0i0 = xsgn(g.y, sm);
    const float c1r0 = xsgn(g.z, sm);
    const float c0i1 = xsgn(g.y, sm ^ 0x80000000u);
    const float c1r1 = xsgn(g.z, sm ^ 0x80000000u);

    // phase 1: gather ALL partner values (batched exchanges; olds captured
    // before any update, so phase 2 is order-free). +32 live VGPRs by design.
    float br[16], bi[16];
    #pragma unroll
    for (int r = 0; r < 16; ++r) {
        float pr = ar[r ^ RM], pi = ai[r ^ RM];
        if constexpr (LM != 0) { pr = shxm<LM>(pr); pi = shxm<LM>(pi); }
        br[r] = pr; bi[r] = pi;
    }
    // phase 2: 16 independent 2x2 updates (16-way ILP)
    #pragma unroll
    for (int r = 0; r < 16; ++r) {
        const bool c1 = (__builtin_popcount(r & SRM) & 1) != 0;  // compile-time
        const float c0i = c1 ? c0i1 : c0i0;
        const float c1r = c1 ? c1r1 : c1r0;
        const float nr = c0r*ar[r] - c0i*ai[r] + c1r*br[r] - c1i*bi[r];
        const float ni = c0r*ai[r] + c0i*ar[r] + c1r*bi[r] + c1i*br[r];
        ar[r] = nr; ai[r] = ni;
    }
}

#define GATE(L, Q) apply_gate<lm_of(L,Q), rm_of(L,Q), slm_of(L,Q), srm_of(L,Q)>( \
                       ar, ai, lane, gsh4[(L)*8+(Q)])
#define LAYER(L) GATE(L,0); GATE(L,1); GATE(L,2); GATE(L,3); \
                 GATE(L,4); GATE(L,5); GATE(L,6); GATE(L,7);

__global__ __launch_bounds__(256, 4) void qsim(const float* __restrict__ x,
                                               const float* __restrict__ w,
                                               float* __restrict__ out, int B)
{
    __shared__ float4 gsh4[NGATES];  // u00r,u00i,u01r,u01i (row1 = conj structure)

    const int tid = threadIdx.x;
    if (tid < NGATES) {
        float hx = 0.5f * w[tid*3+0];
        float hy = 0.5f * w[tid*3+1];
        float hz = 0.5f * w[tid*3+2];
        float cx = cosf(hx), sx = sinf(hx);
        float cy = cosf(hy), sy = sinf(hy);
        float cz = cosf(hz), sz = sinf(hz);
        // M = RY*RX ; U = RZ*M (row0 only; u11=conj(u00), u10=-conj(u01))
        float m00r = cy*cx,  m00i =  sy*sx;
        float m01r = -sy*cx, m01i = -cy*sx;
        gsh4[tid] = make_float4(cz*m00r + sz*m00i,
                                cz*m00i - sz*m00r,
                                cz*m01r + sz*m01i,
                                cz*m01i - sz*m01r);
    }
    __syncthreads();

    const int lane = tid & 63;
    const int il   = lane & 15;                 // in-sample lane index (amp bits 7:4)
    const int sample = blockIdx.x * 16 + (tid >> 4);
    if (sample >= B) return;

    // ---- encoding + layer 0 folded: complex product state (validated R6) ----
    // Per qubit q: (alpha,beta) = U0q * (cos(x/2), sin(x/2))^T with
    // u10=-conj(u01), u11=conj(u00):
    //   alpha = (gx*c + gz*s,  gy*c + gw*s)
    //   beta  = (gx*s - gz*c,  gw*c - gy*s)
    const float4* xp = (const float4*)(x + sample * 8);
    float4 xa = xp[0], xb = xp[1];
    float xs[8] = {xa.x, xa.y, xa.z, xa.w, xb.x, xb.y, xb.z, xb.w};
    float arf[8], aif[8], brf[8], bif[8];
    #pragma unroll
    for (int q = 0; q < 8; ++q) {
        float c, s;
        __sincosf(0.5f * xs[q], &s, &c);
        const float4 g = gsh4[q];
        arf[q] = g.x*c + g.z*s;
        aif[q] = g.y*c + g.w*s;
        brf[q] = g.x*s - g.z*c;
        bif[q] = g.w*c - g.y*s;
    }
    // lane factor F = prod_{q=0..3} (lane bit 3-q ? beta : alpha), complex
    float Fr = (il & 8) ? brf[0] : arf[0];
    float Fi = (il & 8) ? bif[0] : aif[0];
    #pragma unroll
    for (int q = 1; q < 4; ++q) {
        const int bit = il & (8 >> q);
        const float gr = bit ? brf[q] : arf[q];
        const float gi = bit ? bif[q] : aif[q];
        const float nr = Fr*gr - Fi*gi;
        const float ni = Fr*gi + Fi*gr;
        Fr = nr; Fi = ni;
    }
    // register tree (complex): reg bit3=q4, b2=q5, b1=q6, b0=q7
    float t67r[4], t67i[4];
    #pragma unroll
    for (int b6 = 0; b6 < 2; ++b6)
        #pragma unroll
        for (int b7 = 0; b7 < 2; ++b7) {
            const float x6r = b6 ? brf[6] : arf[6], x6i = b6 ? bif[6] : aif[6];
            const float x7r = b7 ? brf[7] : arf[7], x7i = b7 ? bif[7] : aif[7];
            t67r[b6*2+b7] = x6r*x7r - x6i*x7i;
            t67i[b6*2+b7] = x6r*x7i + x6i*x7r;
        }
    float v57r[8], v57i[8];
    #pragma unroll
    for (int b5 = 0; b5 < 2; ++b5) {
        const float x5r = b5 ? brf[5] : arf[5], x5i = b5 ? bif[5] : aif[5];
        #pragma unroll
        for (int k = 0; k < 4; ++k) {
            v57r[b5*4+k] = x5r*t67r[k] - x5i*t67i[k];
            v57i[b5*4+k] = x5r*t67i[k] + x5i*t67r[k];
        }
    }
    float b4r[2], b4i[2];
    #pragma unroll
    for (int b4 = 0; b4 < 2; ++b4) {
        const float x4r = b4 ? brf[4] : arf[4], x4i = b4 ? bif[4] : aif[4];
        b4r[b4] = x4r*Fr - x4i*Fi;
        b4i[b4] = x4r*Fi + x4i*Fr;
    }
    float ar[16], ai[16];
    #pragma unroll
    for (int r = 0; r < 16; ++r) {
        const int hi = (r >> 3) & 1, lo = r & 7;
        ar[r] = b4r[hi]*v57r[lo] - b4i[hi]*v57i[lo];
        ai[r] = b4r[hi]*v57i[lo] + b4i[hi]*v57r[lo];
    }

    // ---- layers 1..3 of fused gates (CNOTs deferred; layer 0 folded above) ----
    LAYER(1)
    LAYER(2)
    LAYER(3)

    // ---- measurement ----
    float p[16];
    #pragma unroll
    for (int r = 0; r < 16; ++r) p[r] = ar[r]*ar[r] + ai[r]*ai[r];

    // register-level signed sums: A_k = sum_r (-1)^{bit k of r} p[r]
    float s0[8], d0[8];
    #pragma unroll
    for (int k = 0; k < 8; ++k) { s0[k] = p[2*k] + p[2*k+1]; d0[k] = p[2*k] - p[2*k+1]; }
    float A0 = ((d0[0]+d0[1]) + (d0[2]+d0[3])) + ((d0[4]+d0[5]) + (d0[6]+d0[7]));
    float s1[4], d1[4];
    #pragma unroll
    for (int k = 0; k < 4; ++k) { s1[k] = s0[2*k] + s0[2*k+1]; d1[k] = s0[2*k] - s0[2*k+1]; }
    float A1 = (d1[0]+d1[1]) + (d1[2]+d1[3]);
    float s2[2], d2[2];
    #pragma unroll
    for (int k = 0; k < 2; ++k) { s2[k] = s1[2*k] + s1[2*k+1]; d2[k] = s1[2*k] - s1[2*k+1]; }
    float A2 = d2[0] + d2[1];
    float A3 = s2[0] - s2[1];
    float P  = s2[0] + s2[1];

    // per-lane sign bitmasks for lane bits
    const unsigned sg1 = (unsigned)(il & 1) << 31;
    const unsigned sg2 = (unsigned)(il & 2) << 30;
    const unsigned sg4 = (unsigned)(il & 4) << 29;
    const unsigned sg8 = (unsigned)(il & 8) << 28;

    // 4-stage WHT of P over the 16-lane group: lane j holds sum_i (-1)^{i.j} P_i
    float wP = P;
    { float t = shxm<1>(wP); wP = t + xsgn(wP, sg1); }
    { float t = shxm<2>(wP); wP = t + xsgn(wP, sg2); }
    { float t = shxm<4>(wP); wP = t + xsgn(wP, sg4); }
    { float t = shxm<8>(wP); wP = t + xsgn(wP, sg8); }
    // v0 at il=8, v1 at il=4, v2 at il=2, v3 at il=1

    // signed lane sums for v4..v7 (sign = one lane bit), result in all lanes
    float a3 = xsgn(A3, sg8);
    a3 += shxm<1>(a3); a3 += shxm<2>(a3); a3 += shxm<4>(a3); a3 += shxm<8>(a3);
    float a2 = xsgn(A2, sg4);
    a2 += shxm<1>(a2); a2 += shxm<2>(a2); a2 += shxm<4>(a2); a2 += shxm<8>(a2);
    float a1 = xsgn(A1, sg2);
    a1 += shxm<1>(a1); a1 += shxm<2>(a1); a1 += shxm<4>(a1); a1 += shxm<8>(a1);
    float a0 = xsgn(A0, sg1);
    a0 += shxm<1>(a0); a0 += shxm<2>(a0); a0 += shxm<4>(a0); a0 += shxm<8>(a0);

    float* op = out + sample * 8;
    if (il == 8)      { op[0] = wP; op[4] = a3; }
    else if (il == 4) { op[1] = wP; op[5] = a2; }
    else if (il == 2) { op[2] = wP; op[6] = a1; }
    else if (il == 1) { op[3] = wP; op[7] = a0; }
}

extern "C" void kernel_launch(void* const* d_in, const int* in_sizes, int n_in,
                              void* d_out, int out_size, void* d_ws, size_t ws_size,
                              hipStream_t stream) {
    const float* x = (const float*)d_in[0];
    const float* w = (const float*)d_in[1];
    float* out = (float*)d_out;
    const int B = in_sizes[0] / 8;           // 16384 samples
    const int blocks = (B + 15) / 16;        // 16 samples per 256-thread block
    qsim<<<blocks, 256, 0, stream>>>(x, w, out, B);
}